// Round 1
// baseline (14777.919 us; speedup 1.0000x reference)
//
#include <hip/hip_runtime.h>
#include <math.h>

#define KW 24
#define BSZn 64
#define PLY 32
#define EMB 512
#define HSZ 512
#define BROWS 1536            // BSZ*KW rows per task
#define RTOT 4608             // 3*BROWS
#define G4 2048               // 4*HSZ
#define NFUSE 2560            // 4*HSZ + HSZ (gates + q fused)

__device__ __forceinline__ float sigmoidf_(float x) { return 1.0f / (1.0f + expf(-x)); }

// ---------------- W3 = [W_ih|W_hh ; 0|Wq], bias3 = [b_ih+b_hh ; bq] ----------------
__global__ void w3cat_kernel(const float* __restrict__ W_ih, const float* __restrict__ W_hh,
                             const float* __restrict__ Wq, const float* __restrict__ b_ih,
                             const float* __restrict__ b_hh, const float* __restrict__ bq,
                             float* __restrict__ W3, float* __restrict__ bias3)
{
    int n = blockIdx.x;          // 0..2559
    int tid = threadIdx.x;
    float* w = W3 + (size_t)n * 1024;
    if (n < G4) {
        for (int k = tid; k < 512; k += blockDim.x) {
            w[k]       = W_ih[(size_t)n * 512 + k];
            w[512 + k] = W_hh[(size_t)n * 512 + k];
        }
        if (tid == 0) bias3[n] = b_ih[n] + b_hh[n];
    } else {
        int j = n - G4;
        for (int k = tid; k < 512; k += blockDim.x) {
            w[k]       = 0.0f;
            w[512 + k] = Wq[(size_t)j * 512 + k];
        }
        if (tid == 0) bias3[n] = bq[j];
    }
}

// ---------------- h0 = enc.sum(axis=1) -> ab[:,512:] (h state) and c state ----------------
__global__ void h0init_kernel(const float* __restrict__ home, const float* __restrict__ vis,
                              const float* __restrict__ team,
                              float* __restrict__ ab, float* __restrict__ cst)
{
    int row = blockIdx.x;                 // 0..4607
    int tid = threadIdx.x;                // 256
    int tau = row / BROWS, r = row % BROWS;
    int bb = r / KW, kw = r % KW;
    const float* enc = (tau == 0) ? home : (tau == 1) ? vis : team;
    const float* base = enc + ((size_t)(kw * BSZn + bb) * PLY) * 512;
    for (int e = tid; e < 512; e += blockDim.x) {
        float s = 0.0f;
        for (int p = 0; p < PLY; ++p) s += base[(size_t)p * 512 + e];
        ab[(size_t)row * 1024 + 512 + e] = s;
        cst[(size_t)row * 512 + e] = s;
    }
}

// ---------------- x_t gather into ab[:, 0:512] ----------------
__global__ void xgather_kernel(const float* __restrict__ home, const float* __restrict__ vis,
                               const float* __restrict__ team,
                               const int* __restrict__ hidx, const int* __restrict__ vidx,
                               const int* __restrict__ tidx,
                               const float* __restrict__ init_embed,
                               float* __restrict__ ab, int t)
{
    int gid = blockIdx.x * blockDim.x + threadIdx.x;   // over 4608*128 float4
    int row = gid >> 7, c4 = gid & 127;
    const float4* src;
    if (t == 0) {
        src = (const float4*)init_embed + c4;
    } else {
        int tau = row / BROWS, r = row % BROWS;
        const int* idx = (tau == 0) ? hidx : (tau == 1) ? vidx : tidx;
        int j = idx[r * PLY + (t - 1)];
        const float* enc = (tau == 0) ? home : (tau == 1) ? vis : team;
        int bb = r / KW, kw = r % KW;
        src = (const float4*)(enc + ((size_t)(kw * BSZn + bb) * PLY + j) * 512) + c4;
    }
    ((float4*)(ab + (size_t)row * 1024))[c4] = *src;
}

// ---------------- tiled f32 GEMM: C = A * B^T + bias ----------------
// A: M x K row-major (GATHER: rows gathered from enc4 layout), B: N x K row-major.
#define BM 128
#define BN 128
#define BKK 16

template <bool GATHER>
__global__ __launch_bounds__(256) void gemm_k(
    const float* __restrict__ A0, const float* __restrict__ A1, const float* __restrict__ A2,
    int lda,
    const float* __restrict__ B, int ldb,
    const float* __restrict__ bias,
    float* __restrict__ C, int ldc, int K)
{
    __shared__ float As[BKK][BM + 4];
    __shared__ float Bs[BKK][BN + 4];

    int bm = blockIdx.x, bn = blockIdx.y;
    int tid = threadIdx.x;
    int tm = tid / 16, tn = tid % 16;    // 16x16 threads, each 8x8 outputs
    int lrow = tid >> 2;                 // 0..63 (loader row)
    int lc4  = tid & 3;                  // float4 column index

    const float* a_src0;
    const float* a_src1;
    if (!GATHER) {
        a_src0 = A0 + (size_t)(bm * BM + lrow) * lda;
        a_src1 = a_src0 + (size_t)64 * lda;
    } else {
        int R0 = bm * BM;
        int tau = R0 / (BROWS * PLY);
        const float* enc = (tau == 0) ? A0 : (tau == 1) ? A1 : A2;
        int R = R0 + lrow;
        int rr = R % (BROWS * PLY); int r = rr >> 5; int p = rr & 31;
        int bb = r / KW, kw = r % KW;
        a_src0 = enc + ((size_t)(kw * BSZn + bb) * PLY + p) * 512;
        R = R0 + lrow + 64;
        rr = R % (BROWS * PLY); r = rr >> 5; p = rr & 31;
        bb = r / KW; kw = r % KW;
        a_src1 = enc + ((size_t)(kw * BSZn + bb) * PLY + p) * 512;
    }
    const float* b_src0 = B + (size_t)(bn * BN + lrow) * ldb;
    const float* b_src1 = b_src0 + (size_t)64 * ldb;

    float acc[8][8];
    #pragma unroll
    for (int i = 0; i < 8; ++i)
        #pragma unroll
        for (int j = 0; j < 8; ++j) acc[i][j] = 0.0f;

    for (int k0 = 0; k0 < K; k0 += BKK) {
        float4 a0 = *(const float4*)(a_src0 + k0 + lc4 * 4);
        float4 a1 = *(const float4*)(a_src1 + k0 + lc4 * 4);
        float4 b0 = *(const float4*)(b_src0 + k0 + lc4 * 4);
        float4 b1 = *(const float4*)(b_src1 + k0 + lc4 * 4);
        __syncthreads();   // previous iteration's reads complete
        As[lc4 * 4 + 0][lrow] = a0.x; As[lc4 * 4 + 1][lrow] = a0.y;
        As[lc4 * 4 + 2][lrow] = a0.z; As[lc4 * 4 + 3][lrow] = a0.w;
        As[lc4 * 4 + 0][lrow + 64] = a1.x; As[lc4 * 4 + 1][lrow + 64] = a1.y;
        As[lc4 * 4 + 2][lrow + 64] = a1.z; As[lc4 * 4 + 3][lrow + 64] = a1.w;
        Bs[lc4 * 4 + 0][lrow] = b0.x; Bs[lc4 * 4 + 1][lrow] = b0.y;
        Bs[lc4 * 4 + 2][lrow] = b0.z; Bs[lc4 * 4 + 3][lrow] = b0.w;
        Bs[lc4 * 4 + 0][lrow + 64] = b1.x; Bs[lc4 * 4 + 1][lrow + 64] = b1.y;
        Bs[lc4 * 4 + 2][lrow + 64] = b1.z; Bs[lc4 * 4 + 3][lrow + 64] = b1.w;
        __syncthreads();
        #pragma unroll
        for (int k = 0; k < BKK; ++k) {
            float af[8], bf[8];
            *(float4*)&af[0] = *(const float4*)&As[k][tm * 8];
            *(float4*)&af[4] = *(const float4*)&As[k][tm * 8 + 4];
            *(float4*)&bf[0] = *(const float4*)&Bs[k][tn * 8];
            *(float4*)&bf[4] = *(const float4*)&Bs[k][tn * 8 + 4];
            #pragma unroll
            for (int i = 0; i < 8; ++i)
                #pragma unroll
                for (int j = 0; j < 8; ++j)
                    acc[i][j] = fmaf(af[i], bf[j], acc[i][j]);
        }
    }

    int row0 = bm * BM + tm * 8;
    int col0 = bn * BN + tn * 8;
    float bv[8];
    if (bias) {
        *(float4*)&bv[0] = *(const float4*)&bias[col0];
        *(float4*)&bv[4] = *(const float4*)&bias[col0 + 4];
    } else {
        #pragma unroll
        for (int j = 0; j < 8; ++j) bv[j] = 0.0f;
    }
    #pragma unroll
    for (int i = 0; i < 8; ++i) {
        float* cr = C + (size_t)(row0 + i) * ldc + col0;
        float4 o0, o1;
        o0.x = acc[i][0] + bv[0]; o0.y = acc[i][1] + bv[1];
        o0.z = acc[i][2] + bv[2]; o0.w = acc[i][3] + bv[3];
        o1.x = acc[i][4] + bv[4]; o1.y = acc[i][5] + bv[5];
        o1.z = acc[i][6] + bv[6]; o1.w = acc[i][7] + bv[7];
        *(float4*)cr = o0;
        *(float4*)(cr + 4) = o1;
    }
}

// ---------------- LSTM cell elementwise ----------------
__global__ void lstm_kernel(const float* __restrict__ gbuf, float* __restrict__ ab,
                            float* __restrict__ cst)
{
    int idx = blockIdx.x * blockDim.x + threadIdx.x;   // 4608*512
    int row = idx >> 9, e = idx & 511;
    const float* g = gbuf + (size_t)row * NFUSE;
    float gi = g[e], gf = g[512 + e], gg = g[1024 + e], go = g[1536 + e];
    float c = cst[idx];
    c = sigmoidf_(gf) * c + sigmoidf_(gi) * tanhf(gg);
    float h = sigmoidf_(go) * tanhf(c);
    cst[idx] = c;
    ab[(size_t)row * 1024 + 512 + e] = h;
}

// ---------------- attention + log_softmax + argmax for step t ----------------
__global__ __launch_bounds__(256) void attn_kernel(
    const float* __restrict__ gbuf,       // q at cols 2048..2559
    const float* __restrict__ ctx,        // [4608*32][512]
    const float* __restrict__ vvec,       // [512]
    float* __restrict__ out, int t)
{
    int row = blockIdx.x;                 // 0..4607
    int tid = threadIdx.x;
    int lane = tid & 63, w = tid >> 6;    // 4 waves
    __shared__ float sc_s[PLY];

    const float* q = gbuf + (size_t)row * NFUSE + G4;
    const float* ctxr = ctx + (size_t)row * PLY * 512;

    float qv[8], vv[8];
    #pragma unroll
    for (int j = 0; j < 8; ++j) { qv[j] = q[lane + 64 * j]; vv[j] = vvec[lane + 64 * j]; }

    #pragma unroll
    for (int pp = 0; pp < 8; ++pp) {
        int p = w * 8 + pp;
        const float* cp = ctxr + (size_t)p * 512;
        float acc = 0.0f;
        #pragma unroll
        for (int j = 0; j < 8; ++j)
            acc += tanhf(qv[j] + cp[lane + 64 * j]) * vv[j];
        #pragma unroll
        for (int off = 32; off; off >>= 1) acc += __shfl_down(acc, off);
        if (lane == 0) sc_s[p] = acc;
    }
    __syncthreads();

    if (tid < 64) {
        float x = (lane < PLY) ? sc_s[lane] : -3.4e38f;
        float bvv = x; int bi = (lane < PLY) ? lane : 1000;
        #pragma unroll
        for (int off = 32; off; off >>= 1) {
            float ov = __shfl_xor(bvv, off);
            int oi = __shfl_xor(bi, off);
            if (ov > bvv || (ov == bvv && oi < bi)) { bvv = ov; bi = oi; }
        }
        float e = expf(x - bvv);
        float s = e;
        #pragma unroll
        for (int off = 32; off; off >>= 1) s += __shfl_xor(s, off);
        float lse = logf(s);

        int tau = row / BROWS, r = row % BROWS;
        size_t attbase = (size_t)tau * (BROWS * PLY * PLY) + (size_t)r * (PLY * PLY) + (size_t)t * PLY;
        if (lane < PLY) out[attbase + lane] = x - bvv - lse;
        if (lane == 0) {
            size_t argbase = (size_t)3 * (BROWS * PLY * PLY) + (size_t)tau * (BROWS * PLY) + (size_t)r * PLY + t;
            out[argbase] = (float)bi;
        }
    }
}

extern "C" void kernel_launch(void* const* d_in, const int* in_sizes, int n_in,
                              void* d_out, int out_size, void* d_ws, size_t ws_size,
                              hipStream_t stream)
{
    const float* home = (const float*)d_in[0];
    const int*   hidx = (const int*)d_in[1];
    const float* vis  = (const float*)d_in[2];
    const int*   vidx = (const int*)d_in[3];
    const float* team = (const float*)d_in[4];
    const int*   tidx = (const int*)d_in[5];
    const float* init_embed = (const float*)d_in[6];
    const float* W_ih = (const float*)d_in[7];
    const float* W_hh = (const float*)d_in[8];
    const float* b_ih = (const float*)d_in[9];
    const float* b_hh = (const float*)d_in[10];
    const float* Wq   = (const float*)d_in[11];
    const float* bq   = (const float*)d_in[12];
    const float* Wc   = (const float*)d_in[13];
    const float* vvec = (const float*)d_in[14];
    float* out = (float*)d_out;
    (void)in_sizes; (void)n_in; (void)out_size; (void)ws_size;

    float* ws = (float*)d_ws;
    float* W3    = ws; ws += (size_t)NFUSE * 1024;     // 2.6M
    float* bias3 = ws; ws += NFUSE;
    float* ab    = ws; ws += (size_t)RTOT * 1024;      // [x_t | h]
    float* cst   = ws; ws += (size_t)RTOT * 512;
    float* gbuf  = ws; ws += (size_t)RTOT * NFUSE;     // [gates | q]
    float* ctx   = ws; ws += (size_t)RTOT * PLY * 512; // 302 MB

    w3cat_kernel<<<NFUSE, 256, 0, stream>>>(W_ih, W_hh, Wq, b_ih, b_hh, bq, W3, bias3);
    h0init_kernel<<<RTOT, 256, 0, stream>>>(home, vis, team, ab, cst);
    // ctx = enc @ Wc^T : M=147456, N=512, K=512, gathered A rows
    gemm_k<true><<<dim3(RTOT * PLY / BM, 512 / BN), 256, 0, stream>>>(
        home, vis, team, 0, Wc, 512, nullptr, ctx, 512, 512);

    for (int t = 0; t < PLY; ++t) {
        xgather_kernel<<<RTOT * 128 / 256, 256, 0, stream>>>(
            home, vis, team, hidx, vidx, tidx, init_embed, ab, t);
        // [gates_t | q_{t-1}] = [x_t | h_{t-1}] @ W3^T + bias3
        gemm_k<false><<<dim3(RTOT / BM, NFUSE / BN), 256, 0, stream>>>(
            ab, nullptr, nullptr, 1024, W3, 1024, bias3, gbuf, NFUSE, 1024);
        if (t >= 1)
            attn_kernel<<<RTOT, 256, 0, stream>>>(gbuf, ctx, vvec, out, t - 1);
        lstm_kernel<<<RTOT * 512 / 256, 256, 0, stream>>>(gbuf, ab, cst);
    }
    // final q_31 = h_31 @ Wq^T + bq (uses zero-padded left half of W3 rows 2048+)
    gemm_k<false><<<dim3(RTOT / BM, 512 / BN), 256, 0, stream>>>(
        ab, nullptr, nullptr, 1024, W3 + (size_t)G4 * 1024, 1024, bias3 + G4,
        gbuf + G4, NFUSE, 1024);
    attn_kernel<<<RTOT, 256, 0, stream>>>(gbuf, ctx, vvec, out, 31);
}

// Round 3
// 12283.624 us; speedup vs baseline: 1.2031x; 1.2031x over previous
//
#include <hip/hip_runtime.h>
#include <math.h>

#define KW 24
#define BSZn 64
#define PLY 32
#define HSZ 512
#define BROWS 1536            // BSZ*KW rows per task
#define RTOT 4608             // 3*BROWS
#define G4 2048               // 4*HSZ
#define NFUSE 2560            // 4*HSZ + HSZ
#define BM 128
#define BN 128
#define BK 16

__device__ __forceinline__ float sigmoidf_(float x) { return 1.0f / (1.0f + expf(-x)); }

// W3 rows interleaved: n<2048 -> quad=n>>2, gate=n&3, source row gate*512+quad of [W_ih|W_hh]
//                      n>=2048 -> [0 | Wq[n-2048]] ; bias3 likewise
__global__ void w3cat_kernel(const float* __restrict__ W_ih, const float* __restrict__ W_hh,
                             const float* __restrict__ Wq, const float* __restrict__ b_ih,
                             const float* __restrict__ b_hh, const float* __restrict__ bq,
                             float* __restrict__ W3, float* __restrict__ bias3)
{
    int n = blockIdx.x;          // 0..2559
    int tid = threadIdx.x;
    float* w = W3 + (size_t)n * 1024;
    if (n < G4) {
        int src = (n & 3) * 512 + (n >> 2);
        for (int k = tid; k < 512; k += blockDim.x) {
            w[k]       = W_ih[(size_t)src * 512 + k];
            w[512 + k] = W_hh[(size_t)src * 512 + k];
        }
        if (tid == 0) bias3[n] = b_ih[src] + b_hh[src];
    } else {
        int j = n - G4;
        for (int k = tid; k < 512; k += blockDim.x) {
            w[k]       = 0.0f;
            w[512 + k] = Wq[(size_t)j * 512 + k];
        }
        if (tid == 0) bias3[n] = bq[j];
    }
}

// h0 = enc.sum(axis=1) -> hbuf0 (h state) and cst (c state)
__global__ void h0init_kernel(const float* __restrict__ home, const float* __restrict__ vis,
                              const float* __restrict__ team,
                              float* __restrict__ hbuf0, float* __restrict__ cst)
{
    int row = blockIdx.x;                 // 0..4607
    int tid = threadIdx.x;                // 256
    int tau = row / BROWS, r = row % BROWS;
    int bb = r / KW, kw = r % KW;
    const float* enc = (tau == 0) ? home : (tau == 1) ? vis : team;
    const float* base = enc + ((size_t)(kw * BSZn + bb) * PLY) * 512;
    for (int e = tid; e < 512; e += blockDim.x) {
        float s = 0.0f;
        for (int p = 0; p < PLY; ++p) s += base[(size_t)p * 512 + e];
        hbuf0[(size_t)row * 512 + e] = s;
        cst[(size_t)row * 512 + e] = s;
    }
}

// ---------------- ctx = enc @ Wc^T (gathered A rows), f32 out ----------------
__global__ __launch_bounds__(256) void gemm_ctx(
    const float* __restrict__ A0, const float* __restrict__ A1, const float* __restrict__ A2,
    const float* __restrict__ B, float* __restrict__ C)
{
    __shared__ float As[BK][BM + 4];
    __shared__ float Bs[BK][BN + 4];
    int bm = blockIdx.x, bn = blockIdx.y;
    int tid = threadIdx.x;
    int tm = tid >> 4, tn = tid & 15;
    int lrow = tid >> 2, lc4 = tid & 3;

    int R0 = bm * BM;
    int tau = R0 / (BROWS * PLY);
    const float* enc = (tau == 0) ? A0 : (tau == 1) ? A1 : A2;
    int R = R0 + lrow;
    int rr = R % (BROWS * PLY); int r = rr >> 5; int p = rr & 31;
    const float* a_src0 = enc + ((size_t)((r % KW) * BSZn + r / KW) * PLY + p) * 512;
    R = R0 + lrow + 64;
    rr = R % (BROWS * PLY); r = rr >> 5; p = rr & 31;
    const float* a_src1 = enc + ((size_t)((r % KW) * BSZn + r / KW) * PLY + p) * 512;
    const float* b_src0 = B + (size_t)(bn * BN + lrow) * 512;
    const float* b_src1 = b_src0 + (size_t)64 * 512;

    float acc[8][8];
    #pragma unroll
    for (int i = 0; i < 8; ++i)
        #pragma unroll
        for (int j = 0; j < 8; ++j) acc[i][j] = 0.0f;

    float4 a0 = *(const float4*)(a_src0 + lc4 * 4);
    float4 a1 = *(const float4*)(a_src1 + lc4 * 4);
    float4 b0 = *(const float4*)(b_src0 + lc4 * 4);
    float4 b1 = *(const float4*)(b_src1 + lc4 * 4);

    for (int it = 0; it < 512 / BK; ++it) {
        As[lc4 * 4 + 0][lrow] = a0.x; As[lc4 * 4 + 1][lrow] = a0.y;
        As[lc4 * 4 + 2][lrow] = a0.z; As[lc4 * 4 + 3][lrow] = a0.w;
        As[lc4 * 4 + 0][lrow + 64] = a1.x; As[lc4 * 4 + 1][lrow + 64] = a1.y;
        As[lc4 * 4 + 2][lrow + 64] = a1.z; As[lc4 * 4 + 3][lrow + 64] = a1.w;
        Bs[lc4 * 4 + 0][lrow] = b0.x; Bs[lc4 * 4 + 1][lrow] = b0.y;
        Bs[lc4 * 4 + 2][lrow] = b0.z; Bs[lc4 * 4 + 3][lrow] = b0.w;
        Bs[lc4 * 4 + 0][lrow + 64] = b1.x; Bs[lc4 * 4 + 1][lrow + 64] = b1.y;
        Bs[lc4 * 4 + 2][lrow + 64] = b1.z; Bs[lc4 * 4 + 3][lrow + 64] = b1.w;
        __syncthreads();
        if (it + 1 < 512 / BK) {
            int k0 = (it + 1) * BK + lc4 * 4;
            a0 = *(const float4*)(a_src0 + k0);
            a1 = *(const float4*)(a_src1 + k0);
            b0 = *(const float4*)(b_src0 + k0);
            b1 = *(const float4*)(b_src1 + k0);
        }
        #pragma unroll
        for (int k = 0; k < BK; ++k) {
            float af[8], bf[8];
            *(float4*)&af[0] = *(const float4*)&As[k][tm * 8];
            *(float4*)&af[4] = *(const float4*)&As[k][tm * 8 + 4];
            *(float4*)&bf[0] = *(const float4*)&Bs[k][tn * 8];
            *(float4*)&bf[4] = *(const float4*)&Bs[k][tn * 8 + 4];
            #pragma unroll
            for (int i = 0; i < 8; ++i)
                #pragma unroll
                for (int j = 0; j < 8; ++j)
                    acc[i][j] = fmaf(af[i], bf[j], acc[i][j]);
        }
        __syncthreads();
    }
    int row0 = bm * BM + tm * 8;
    int col0 = bn * BN + tn * 8;
    #pragma unroll
    for (int i = 0; i < 8; ++i) {
        float* cr = C + (size_t)(row0 + i) * 512 + col0;
        float4 o0, o1;
        o0.x = acc[i][0]; o0.y = acc[i][1]; o0.z = acc[i][2]; o0.w = acc[i][3];
        o1.x = acc[i][4]; o1.y = acc[i][5]; o1.z = acc[i][6]; o1.w = acc[i][7];
        *(float4*)cr = o0;
        *(float4*)(cr + 4) = o1;
    }
}

// ------- step GEMM: [gates_t | q_{t-1}] = [x_t | h_{t-1}] @ W3^T + bias3 -------
// A gathered on the fly (k<512: enc[idx], k>=512: hin). Gate blocks (bn<16) fuse
// the LSTM cell in the epilogue (W3 rows interleaved i,f,g,o). q blocks (bn>=16)
// start K at 512 (left half of Wq rows is zero) and write Q4 slot tq.
__global__ __launch_bounds__(256) void gemm_step(
    const float* __restrict__ home, const float* __restrict__ vis, const float* __restrict__ team,
    const int* __restrict__ hidx, const int* __restrict__ vidx, const int* __restrict__ tidx,
    const float* __restrict__ init_embed,
    const float* __restrict__ hin,
    const float* __restrict__ W3, const float* __restrict__ bias3,
    float* __restrict__ cst, float* __restrict__ hout,
    float* __restrict__ Q4, int t, int bn_off, int tq)
{
    __shared__ float As[BK][BM + 4];
    __shared__ float Bs[BK][BN + 4];
    int bm = blockIdx.x, bn = blockIdx.y + bn_off;
    int tid = threadIdx.x;
    int tm = tid >> 4, tn = tid & 15;
    int lrow = tid >> 2, lc4 = tid & 3;
    int kstart = (bn >= 16) ? 512 : 0;

    int row0g = bm * BM;
    int tau = row0g / BROWS;
    const float* enc = (tau == 0) ? home : (tau == 1) ? vis : team;
    const int* idx = (tau == 0) ? hidx : (tau == 1) ? vidx : tidx;
    int r0 = row0g % BROWS + lrow;
    int r1 = r0 + 64;
    const float* xsrc0; const float* xsrc1;
    if (t == 0) {
        xsrc0 = init_embed; xsrc1 = init_embed;
    } else {
        int j0 = idx[r0 * PLY + (t - 1)];
        int j1 = idx[r1 * PLY + (t - 1)];
        xsrc0 = enc + ((size_t)((r0 % KW) * BSZn + r0 / KW) * PLY + j0) * 512;
        xsrc1 = enc + ((size_t)((r1 % KW) * BSZn + r1 / KW) * PLY + j1) * 512;
    }
    const float* hsrc0 = hin + (size_t)(row0g + lrow) * 512;
    const float* hsrc1 = hsrc0 + (size_t)64 * 512;
    const float* b_src0 = W3 + (size_t)(bn * BN + lrow) * 1024;
    const float* b_src1 = b_src0 + (size_t)64 * 1024;

    float acc[8][8];
    #pragma unroll
    for (int i = 0; i < 8; ++i)
        #pragma unroll
        for (int j = 0; j < 8; ++j) acc[i][j] = 0.0f;

    int nt = (1024 - kstart) / BK;
    int kc = kstart + lc4 * 4;
    float4 a0 = *(const float4*)((kc < 512) ? xsrc0 + kc : hsrc0 + (kc - 512));
    float4 a1 = *(const float4*)((kc < 512) ? xsrc1 + kc : hsrc1 + (kc - 512));
    float4 b0 = *(const float4*)(b_src0 + kc);
    float4 b1 = *(const float4*)(b_src1 + kc);

    for (int it = 0; it < nt; ++it) {
        As[lc4 * 4 + 0][lrow] = a0.x; As[lc4 * 4 + 1][lrow] = a0.y;
        As[lc4 * 4 + 2][lrow] = a0.z; As[lc4 * 4 + 3][lrow] = a0.w;
        As[lc4 * 4 + 0][lrow + 64] = a1.x; As[lc4 * 4 + 1][lrow + 64] = a1.y;
        As[lc4 * 4 + 2][lrow + 64] = a1.z; As[lc4 * 4 + 3][lrow + 64] = a1.w;
        Bs[lc4 * 4 + 0][lrow] = b0.x; Bs[lc4 * 4 + 1][lrow] = b0.y;
        Bs[lc4 * 4 + 2][lrow] = b0.z; Bs[lc4 * 4 + 3][lrow] = b0.w;
        Bs[lc4 * 4 + 0][lrow + 64] = b1.x; Bs[lc4 * 4 + 1][lrow + 64] = b1.y;
        Bs[lc4 * 4 + 2][lrow + 64] = b1.z; Bs[lc4 * 4 + 3][lrow + 64] = b1.w;
        __syncthreads();
        if (it + 1 < nt) {
            int k2 = kstart + (it + 1) * BK + lc4 * 4;
            a0 = *(const float4*)((k2 < 512) ? xsrc0 + k2 : hsrc0 + (k2 - 512));
            a1 = *(const float4*)((k2 < 512) ? xsrc1 + k2 : hsrc1 + (k2 - 512));
            b0 = *(const float4*)(b_src0 + k2);
            b1 = *(const float4*)(b_src1 + k2);
        }
        #pragma unroll
        for (int k = 0; k < BK; ++k) {
            float af[8], bf[8];
            *(float4*)&af[0] = *(const float4*)&As[k][tm * 8];
            *(float4*)&af[4] = *(const float4*)&As[k][tm * 8 + 4];
            *(float4*)&bf[0] = *(const float4*)&Bs[k][tn * 8];
            *(float4*)&bf[4] = *(const float4*)&Bs[k][tn * 8 + 4];
            #pragma unroll
            for (int i = 0; i < 8; ++i)
                #pragma unroll
                for (int j = 0; j < 8; ++j)
                    acc[i][j] = fmaf(af[i], bf[j], acc[i][j]);
        }
        __syncthreads();
    }

    int row0 = bm * BM + tm * 8;
    int col0 = bn * BN + tn * 8;
    float bv[8];
    *(float4*)&bv[0] = *(const float4*)&bias3[col0];
    *(float4*)&bv[4] = *(const float4*)&bias3[col0 + 4];

    if (bn < 16) {
        int q0 = col0 >> 2;   // h-column pair base (covers q0, q0+1)
        #pragma unroll
        for (int i = 0; i < 8; ++i) {
            int row = row0 + i;
            float2 c = *(float2*)(cst + (size_t)row * 512 + q0);
            float gi = acc[i][0] + bv[0], gf = acc[i][1] + bv[1];
            float gg = acc[i][2] + bv[2], go = acc[i][3] + bv[3];
            c.x = sigmoidf_(gf) * c.x + sigmoidf_(gi) * tanhf(gg);
            float h0 = sigmoidf_(go) * tanhf(c.x);
            gi = acc[i][4] + bv[4]; gf = acc[i][5] + bv[5];
            gg = acc[i][6] + bv[6]; go = acc[i][7] + bv[7];
            c.y = sigmoidf_(gf) * c.y + sigmoidf_(gi) * tanhf(gg);
            float h1 = sigmoidf_(go) * tanhf(c.y);
            *(float2*)(cst + (size_t)row * 512 + q0) = c;
            float2 hh; hh.x = h0; hh.y = h1;
            *(float2*)(hout + (size_t)row * 512 + q0) = hh;
        }
    } else {
        int qc = col0 - G4;
        #pragma unroll
        for (int i = 0; i < 8; ++i) {
            float* cr = Q4 + (size_t)(row0 + i) * 2048 + tq * 512 + qc;
            float4 o0, o1;
            o0.x = acc[i][0] + bv[0]; o0.y = acc[i][1] + bv[1];
            o0.z = acc[i][2] + bv[2]; o0.w = acc[i][3] + bv[3];
            o1.x = acc[i][4] + bv[4]; o1.y = acc[i][5] + bv[5];
            o1.z = acc[i][6] + bv[6]; o1.w = acc[i][7] + bv[7];
            *(float4*)cr = o0;
            *(float4*)(cr + 4) = o1;
        }
    }
}

// ------- batched attention for 4 steps: scores+log_softmax+argmax, all f32 -------
__global__ __launch_bounds__(256) void attn4_kernel(
    const float* __restrict__ Q4, const float* __restrict__ ctx,
    const float* __restrict__ vvec, float* __restrict__ out, int tbase)
{
    int row = blockIdx.x;                 // 0..4607
    int tid = threadIdx.x;
    int w = tid >> 6, lane = tid & 63;    // wave w handles t = tbase + w
    __shared__ float sc_s[4][PLY];

    const float* q = Q4 + (size_t)row * 2048 + (size_t)w * 512 + lane * 8;
    const float* ctxr = ctx + (size_t)row * PLY * 512 + lane * 8;
    float qv[8], vv[8];
    *(float4*)&qv[0] = *(const float4*)(q);
    *(float4*)&qv[4] = *(const float4*)(q + 4);
    *(float4*)&vv[0] = *(const float4*)(vvec + lane * 8);
    *(float4*)&vv[4] = *(const float4*)(vvec + lane * 8 + 4);

    for (int p = 0; p < PLY; ++p) {
        const float* cp = ctxr + (size_t)p * 512;
        float cv[8];
        *(float4*)&cv[0] = *(const float4*)(cp);
        *(float4*)&cv[4] = *(const float4*)(cp + 4);
        float acc = 0.0f;
        #pragma unroll
        for (int j = 0; j < 8; ++j) acc += tanhf(qv[j] + cv[j]) * vv[j];
        #pragma unroll
        for (int off = 1; off < 64; off <<= 1) acc += __shfl_xor(acc, off);
        if (lane == 0) sc_s[w][p] = acc;
    }
    __syncthreads();

    if (tid < 128) {
        int w2 = tid >> 5, l = tid & 31;
        float x = sc_s[w2][l];
        float bvv = x; int bi = l;
        #pragma unroll
        for (int off = 1; off < 32; off <<= 1) {
            float ov = __shfl_xor(bvv, off, 32);
            int oi = __shfl_xor(bi, off, 32);
            if (ov > bvv || (ov == bvv && oi < bi)) { bvv = ov; bi = oi; }
        }
        float s = expf(x - bvv);
        #pragma unroll
        for (int off = 1; off < 32; off <<= 1) s += __shfl_xor(s, off, 32);
        float lse = logf(s);
        int t = tbase + w2;
        int tau = row / BROWS, r = row % BROWS;
        out[(size_t)tau * (BROWS * 1024) + (size_t)r * 1024 + t * 32 + l] = x - bvv - lse;
        if (l == 0)
            out[(size_t)3 * (BROWS * 1024) + (size_t)tau * (BROWS * 32) + r * 32 + t] = (float)bi;
    }
}

extern "C" void kernel_launch(void* const* d_in, const int* in_sizes, int n_in,
                              void* d_out, int out_size, void* d_ws, size_t ws_size,
                              hipStream_t stream)
{
    const float* home = (const float*)d_in[0];
    const int*   hidx = (const int*)d_in[1];
    const float* vis  = (const float*)d_in[2];
    const int*   vidx = (const int*)d_in[3];
    const float* team = (const float*)d_in[4];
    const int*   tidx = (const int*)d_in[5];
    const float* init_embed = (const float*)d_in[6];
    const float* W_ih = (const float*)d_in[7];
    const float* W_hh = (const float*)d_in[8];
    const float* b_ih = (const float*)d_in[9];
    const float* b_hh = (const float*)d_in[10];
    const float* Wq   = (const float*)d_in[11];
    const float* bq   = (const float*)d_in[12];
    const float* Wc   = (const float*)d_in[13];
    const float* vvec = (const float*)d_in[14];
    float* out = (float*)d_out;
    (void)in_sizes; (void)n_in; (void)out_size; (void)ws_size;

    float* ws = (float*)d_ws;
    float* W3    = ws; ws += (size_t)NFUSE * 1024;      // 10.5 MB
    float* bias3 = ws; ws += NFUSE;
    float* hbuf0 = ws; ws += (size_t)RTOT * 512;        // 9.4 MB
    float* hbuf1 = ws; ws += (size_t)RTOT * 512;        // 9.4 MB
    float* cst   = ws; ws += (size_t)RTOT * 512;        // 9.4 MB
    float* Q4    = ws; ws += (size_t)RTOT * 2048;       // 37.7 MB (4 q slots)
    float* ctx   = ws;                                  // 302 MB f32
    // total ~378.5 MB (<= round-1-proven 388 MB)

    w3cat_kernel<<<NFUSE, 256, 0, stream>>>(W_ih, W_hh, Wq, b_ih, b_hh, bq, W3, bias3);
    h0init_kernel<<<RTOT, 256, 0, stream>>>(home, vis, team, hbuf0, cst);
    gemm_ctx<<<dim3(RTOT * PLY / BM, 512 / BN), 256, 0, stream>>>(home, vis, team, Wc, ctx);

    for (int t = 0; t < PLY; ++t) {
        const float* hin = (t & 1) ? hbuf1 : hbuf0;
        float* hout = (t & 1) ? hbuf0 : hbuf1;
        int gy = (t == 0) ? 16 : 20;                    // t=0: no q block (q_{-1} unused)
        int tq = (t == 0) ? 0 : ((t - 1) & 3);
        gemm_step<<<dim3(RTOT / BM, gy), 256, 0, stream>>>(
            home, vis, team, hidx, vidx, tidx, init_embed, hin, W3, bias3,
            cst, hout, Q4, t, 0, tq);
        if (t >= 4 && (t & 3) == 0)                     // q_{t-4}..q_{t-1} ready
            attn4_kernel<<<RTOT, 256, 0, stream>>>(Q4, ctx, vvec, out, t - 4);
    }
    // tail: q_31 from h_31 (in hbuf0 since (31+1)&1==0); q-blocks only
    gemm_step<<<dim3(RTOT / BM, 4), 256, 0, stream>>>(
        home, vis, team, hidx, vidx, tidx, init_embed, hbuf0, W3, bias3,
        cst, hbuf1, Q4, 32, 16, 3);
    attn4_kernel<<<RTOT, 256, 0, stream>>>(Q4, ctx, vvec, out, 28);
}